// Round 1
// baseline (2105.027 us; speedup 1.0000x reference)
//
#include <hip/hip_runtime.h>
#include <hip/hip_bf16.h>
#include <cstdint>

#define BT 2048
#define HS 2048
#define HT 4096
#define VOCAB 32000
#define IGNORE_IDX (-100)

#define BM 128
#define BN 128
#define BKE 32            // K elems per LDS tile (m97 config: 16 KB A + 16 KB B, linear, no pad)

typedef __bf16 bf16x8 __attribute__((ext_vector_type(8)));
typedef float  f32x4  __attribute__((ext_vector_type(4)));

__device__ __forceinline__ unsigned short f2bf(float f) {
    unsigned int u = __float_as_uint(f);
    u += 0x7FFFu + ((u >> 16) & 1u);   // RNE
    return (unsigned short)(u >> 16);
}
__device__ __forceinline__ float bf2f(unsigned int h) {
    return __uint_as_float(h << 16);
}
__device__ __forceinline__ void unpack8(const unsigned short* p, float* f) {
    const uint4 u = *(const uint4*)p;
    f[0] = bf2f(u.x & 0xFFFFu); f[1] = bf2f(u.x >> 16);
    f[2] = bf2f(u.y & 0xFFFFu); f[3] = bf2f(u.y >> 16);
    f[4] = bf2f(u.z & 0xFFFFu); f[5] = bf2f(u.z >> 16);
    f[6] = bf2f(u.w & 0xFFFFu); f[7] = bf2f(u.w >> 16);
}

// ---- async global->LDS, 16B per lane (dest must be wave-uniform base + lane*16) ----
typedef const __attribute__((address_space(1))) void glob_cv_t;
typedef __attribute__((address_space(3))) void lds_v_t;
__device__ __forceinline__ void gload_lds16(const void* gp, void* lp) {
    __builtin_amdgcn_global_load_lds((glob_cv_t*)gp, (lds_v_t*)lp, 16, 0, 0);
}

// ---- fp32 -> bf16 conversion pre-pass (pure BW; 8 elems/thread/iter) ----
__global__ __launch_bounds__(256) void cvt_kernel(
    const float* __restrict__ src, unsigned short* __restrict__ dst,
    const unsigned long long n8)
{
    for (unsigned long long i = (unsigned long long)blockIdx.x * 256 + threadIdx.x;
         i < n8; i += (unsigned long long)gridDim.x * 256) {
        const float4 a = *(const float4*)(src + i * 8);
        const float4 b = *(const float4*)(src + i * 8 + 4);
        uint4 o;
        o.x = (unsigned)f2bf(a.x) | ((unsigned)f2bf(a.y) << 16);
        o.y = (unsigned)f2bf(a.z) | ((unsigned)f2bf(a.w) << 16);
        o.z = (unsigned)f2bf(b.x) | ((unsigned)f2bf(b.y) << 16);
        o.w = (unsigned)f2bf(b.z) | ((unsigned)f2bf(b.w) << 16);
        *(uint4*)(dst + i * 8) = o;
    }
}

// C[m][n] = sum_k A[m][k]*B[n][k]; A: BT x K bf16, B: VOCAB x K bf16, C: BT x VOCAB bf16
// m97 structure: linear LDS, global_load_lds width 16, 2 barriers per K-step.
__global__ __launch_bounds__(256) void gemm_bf16_kernel(
    const unsigned short* __restrict__ A,
    const unsigned short* __restrict__ B,
    unsigned short* __restrict__ C,
    const int K)
{
    __shared__ unsigned short As[BM * BKE];   // 8 KB: elem e -> row e/32, col e%32
    __shared__ unsigned short Bs[BN * BKE];

    // XCD-aware bijective swizzle (nwg = 16*250 = 4000, % 8 == 0)
    const int nwg = gridDim.x;
    const int cpx = nwg >> 3;
    const int wg  = (blockIdx.x & 7) * cpx + (blockIdx.x >> 3);
    const int row0 = (wg % (BT / BM)) * BM;   // consecutive wg share B panel
    const int col0 = (wg / (BT / BM)) * BN;

    const int tid  = threadIdx.x;
    const int wave = tid >> 6;
    const int lane = tid & 63;
    const int q    = lane >> 4;
    const int l15  = lane & 15;
    const int wm   = (wave & 1) * 64;
    const int wn   = (wave >> 1) * 64;

    f32x4 acc[4][4];
#pragma unroll
    for (int i = 0; i < 4; ++i)
#pragma unroll
        for (int j = 0; j < 4; ++j)
            acc[i][j] = (f32x4){0.f, 0.f, 0.f, 0.f};

    // staging map: chunk u in {0,1}; elem e = u*2048 + tid*8 ; row = u*64 + tid/4 ; col = (tid&3)*8
    const int sr = tid >> 2;
    const int sc = (tid & 3) * 8;
    const unsigned short* Ag = A + (size_t)(row0 + sr) * K + sc;
    const unsigned short* Bg = B + (size_t)(col0 + sr) * K + sc;
    unsigned short* Al = &As[tid * 8];
    unsigned short* Bl = &Bs[tid * 8];
    const size_t rowskip = (size_t)64 * K;

    for (int kt = 0; kt < K; kt += BKE) {
        gload_lds16(Ag + kt,           Al);
        gload_lds16(Ag + kt + rowskip, Al + 2048);
        gload_lds16(Bg + kt,           Bl);
        gload_lds16(Bg + kt + rowskip, Bl + 2048);
        __syncthreads();   // drains vmcnt(0): DMA writes to LDS complete

        bf16x8 af[4], bfr[4];
#pragma unroll
        for (int i = 0; i < 4; ++i)
            af[i] = *(const bf16x8*)(&As[(wm + i * 16 + l15) * BKE + q * 8]);
#pragma unroll
        for (int j = 0; j < 4; ++j)
            bfr[j] = *(const bf16x8*)(&Bs[(wn + j * 16 + l15) * BKE + q * 8]);

#pragma unroll
        for (int i = 0; i < 4; ++i)
#pragma unroll
            for (int j = 0; j < 4; ++j)
                acc[i][j] = __builtin_amdgcn_mfma_f32_16x16x32_bf16(af[i], bfr[j], acc[i][j], 0, 0, 0);
        __syncthreads();
    }

    // C/D layout: col = lane&15, row = quad*4 + reg  [measured m89/m91]
#pragma unroll
    for (int i = 0; i < 4; ++i) {
        const int rr = row0 + wm + i * 16 + q * 4;
#pragma unroll
        for (int j = 0; j < 4; ++j) {
            const int cc = col0 + wn + j * 16 + l15;
#pragma unroll
            for (int r = 0; r < 4; ++r)
                C[(size_t)(rr + r) * VOCAB + cc] = f2bf(acc[i][j][r]);
        }
    }
}

// one block per row: online logsumexp for student+teacher, then JSD sum
__global__ __launch_bounds__(256) void jsd_row_kernel(
    const unsigned short* __restrict__ SL,
    const unsigned short* __restrict__ TL,
    float* __restrict__ row_out)
{
    const int row  = blockIdx.x;
    const int tid  = threadIdx.x;
    const int wave = tid >> 6;
    const int lane = tid & 63;
    const unsigned short* srow = SL + (size_t)row * VOCAB;
    const unsigned short* trow = TL + (size_t)row * VOCAB;

    __shared__ float red[4][4];
    __shared__ float lse_sh[2];

    float sm = -1e30f, sz = 0.f, tm = -1e30f, tz = 0.f;
    for (int v8 = tid; v8 < VOCAB / 8; v8 += 256) {
        float fs[8], ft[8];
        unpack8(srow + v8 * 8, fs);
        unpack8(trow + v8 * 8, ft);
        float lm = fs[0], lmt = ft[0];
#pragma unroll
        for (int k = 1; k < 8; ++k) { lm = fmaxf(lm, fs[k]); lmt = fmaxf(lmt, ft[k]); }
        float lz = 0.f, lzt = 0.f;
#pragma unroll
        for (int k = 0; k < 8; ++k) { lz += __expf(fs[k] - lm); lzt += __expf(ft[k] - lmt); }
        float nm = fmaxf(sm, lm);
        sz = sz * __expf(sm - nm) + lz * __expf(lm - nm);
        sm = nm;
        nm = fmaxf(tm, lmt);
        tz = tz * __expf(tm - nm) + lzt * __expf(lmt - nm);
        tm = nm;
    }
#pragma unroll
    for (int off = 32; off > 0; off >>= 1) {
        float m2 = __shfl_down(sm, off), z2 = __shfl_down(sz, off);
        float nm = fmaxf(sm, m2);
        sz = sz * __expf(sm - nm) + z2 * __expf(m2 - nm);
        sm = nm;
        m2 = __shfl_down(tm, off); z2 = __shfl_down(tz, off);
        nm = fmaxf(tm, m2);
        tz = tz * __expf(tm - nm) + z2 * __expf(m2 - nm);
        tm = nm;
    }
    if (lane == 0) { red[wave][0] = sm; red[wave][1] = sz; red[wave][2] = tm; red[wave][3] = tz; }
    __syncthreads();
    if (tid == 0) {
        float m = red[0][0], z = red[0][1];
        for (int w = 1; w < 4; ++w) {
            float m2 = red[w][0], z2 = red[w][1];
            float nm = fmaxf(m, m2);
            z = z * __expf(m - nm) + z2 * __expf(m2 - nm);
            m = nm;
        }
        lse_sh[0] = m + logf(z);
        m = red[0][2]; z = red[0][3];
        for (int w = 1; w < 4; ++w) {
            float m2 = red[w][2], z2 = red[w][3];
            float nm = fmaxf(m, m2);
            z = z * __expf(m - nm) + z2 * __expf(m2 - nm);
            m = nm;
        }
        lse_sh[1] = m + logf(z);
    }
    __syncthreads();
    const float slse = lse_sh[0], tlse = lse_sh[1];

    float accv = 0.f;
    for (int v8 = tid; v8 < VOCAB / 8; v8 += 256) {
        float fs[8], ft[8];
        unpack8(srow + v8 * 8, fs);
        unpack8(trow + v8 * 8, ft);
#pragma unroll
        for (int k = 0; k < 8; ++k) {
            const float sp = fs[k] - slse;   // log Q
            const float tp = ft[k] - tlse;   // log P
            const float Q = __expf(sp), P = __expf(tp);
            const float logM = __logf(0.5f * (P + Q) + 1e-38f);
            accv += P * (tp - logM) + Q * (sp - logM);
        }
    }
    accv *= 0.5f;   // beta = 0.5
#pragma unroll
    for (int off = 32; off > 0; off >>= 1) accv += __shfl_down(accv, off);
    if (lane == 0) red[wave][0] = accv;
    __syncthreads();
    if (tid == 0) row_out[row] = red[0][0] + red[1][0] + red[2][0] + red[3][0];
}

__global__ __launch_bounds__(256) void finalize_kernel(
    const float* __restrict__ row_sums,
    const int* __restrict__ labels,
    float* __restrict__ out)
{
    const int tid = threadIdx.x;
    float s = 0.f;
    int   c = 0;
    for (int r = tid; r < BT; r += 256) {
        if (labels[r] != IGNORE_IDX) { s += row_sums[r]; c += 1; }
    }
#pragma unroll
    for (int off = 32; off > 0; off >>= 1) {
        s += __shfl_down(s, off);
        c += __shfl_down(c, off);
    }
    __shared__ float ss[4];
    __shared__ int   cc[4];
    const int wave = tid >> 6, lane = tid & 63;
    if (lane == 0) { ss[wave] = s; cc[wave] = c; }
    __syncthreads();
    if (tid == 0) {
        const float S = ss[0] + ss[1] + ss[2] + ss[3];
        const int   C = cc[0] + cc[1] + cc[2] + cc[3];
        out[0] = S / (float)(C > 0 ? C : 1);
    }
}

extern "C" void kernel_launch(void* const* d_in, const int* in_sizes, int n_in,
                              void* d_out, int out_size, void* d_ws, size_t ws_size,
                              hipStream_t stream)
{
    const float* s_in = (const float*)d_in[0];
    const float* s_w  = (const float*)d_in[1];
    const float* t_in = (const float*)d_in[2];
    const float* t_w  = (const float*)d_in[3];
    const int*   lbl  = (const int*)d_in[4];
    float* out = (float*)d_out;

    char* ws = (char*)d_ws;
    const size_t SZ_SLOG = (size_t)BT * VOCAB * 2;   // 131,072,000
    const size_t SZ_TLOG = SZ_SLOG;                  // 131,072,000
    const size_t SZ_TIN  = (size_t)BT * HT * 2;      //  16,777,216
    const size_t SZ_TW   = (size_t)VOCAB * HT * 2;   // 262,144,000

    unsigned short* s_logits = (unsigned short*)ws;
    unsigned short* t_logits = (unsigned short*)(ws + SZ_SLOG);
    unsigned short* t_in_bf  = (unsigned short*)(ws + SZ_SLOG + SZ_TLOG);
    unsigned short* t_w_bf   = (unsigned short*)(ws + SZ_SLOG + SZ_TLOG + SZ_TIN);
    float* row_sums = (float*)(ws + SZ_SLOG + SZ_TLOG + SZ_TIN + SZ_TW);
    // total ws: ~516 MB

    // student bf16 staging aliases [t_logits .. t_in_bf) — dead before gemm_t/cvt(t_*) write there
    unsigned short* s_in_bf = t_logits;
    unsigned short* s_w_bf  = t_logits + (size_t)BT * HS;

    cvt_kernel<<<1024, 256, 0, stream>>>(s_in, s_in_bf, (unsigned long long)BT * HS / 8);
    cvt_kernel<<<1024, 256, 0, stream>>>(s_w,  s_w_bf,  (unsigned long long)VOCAB * HS / 8);
    gemm_bf16_kernel<<<(BT / BM) * (VOCAB / BN), 256, 0, stream>>>(s_in_bf, s_w_bf, s_logits, HS);

    cvt_kernel<<<1024, 256, 0, stream>>>(t_in, t_in_bf, (unsigned long long)BT * HT / 8);
    cvt_kernel<<<1024, 256, 0, stream>>>(t_w,  t_w_bf,  (unsigned long long)VOCAB * HT / 8);
    gemm_bf16_kernel<<<(BT / BM) * (VOCAB / BN), 256, 0, stream>>>(t_in_bf, t_w_bf, t_logits, HT);

    jsd_row_kernel<<<BT, 256, 0, stream>>>(s_logits, t_logits, row_sums);
    finalize_kernel<<<1, 256, 0, stream>>>(row_sums, lbl, out);
}